// Round 13
// baseline (134.709 us; speedup 1.0000x reference)
//
#include <hip/hip_runtime.h>
#include <cstdint>

typedef __attribute__((ext_vector_type(8))) short short8;
typedef __attribute__((ext_vector_type(16))) float f32x16;
typedef __attribute__((ext_vector_type(4))) unsigned int uint4v;

__device__ inline uint32_t f2bf(float f) {
    union { float f; uint32_t u; } x; x.f = f;
    return (x.u + 0x7FFF + ((x.u >> 16) & 1)) >> 16;
}
__device__ inline uint32_t fbits(float f) {
    union { float f; uint32_t u; } x; x.f = f;
    return x.u;
}
__device__ inline float bflo(uint32_t u) {
    union { uint32_t u; float f; } x; x.u = u << 16; return x.f;
}
__device__ inline float bfhi(uint32_t u) {
    union { uint32_t u; float f; } x; x.u = u & 0xFFFF0000u; return x.f;
}

// ktb: kernel fp32 [9][64][64] -> bf16 (RNE); bias outputs init.
__global__ void k_prep(const float* __restrict__ kk, uint16_t* __restrict__ ktb,
                       const float* __restrict__ buI, const float* __restrict__ blI,
                       float* __restrict__ buO, float* __restrict__ blO) {
    int i = blockIdx.x * 256 + threadIdx.x;
    if (i < 36864) ktb[i] = (uint16_t)f2bf(kk[i]);
    else if (i < 36864 + 256) buO[i - 36864] = buI[i - 36864];
    else if (i < 36864 + 512) blO[i - 36864 - 256] = blI[i - 36864 - 256];
}

// Pass 1: build X (bf16) in MFMA-fragment order.
// tid <-> 16-B piece: tid = ((img*1024 + site)*4 + kidx)*64 + l
//   piece elem e: value = src[b][site][co][o], co = kidx*16+(l>>5)*8+e, o = l&31.
__global__ __launch_bounds__(256) void k_xform(
    const float* __restrict__ wu, const float* __restrict__ wl,
    uint4v* __restrict__ X)
{
    int tid  = blockIdx.x * 256 + threadIdx.x;   // 16384 blocks -> 4Mi pieces
    int l    = tid & 63;
    int kidx = (tid >> 6) & 3;
    int site = (tid >> 8) & 1023;
    int img  = tid >> 18;                        // b*2 + src
    int b    = img >> 1;
    const float* src = (img & 1) ? wl : wu;
    int o = l & 31, ch = l >> 5;

    const float* p = src + ((size_t)b * 65536 + (size_t)site * 64
                            + kidx * 16 + ch * 8) * 32 + o;
    uint4v w;
    #pragma unroll
    for (int pr = 0; pr < 4; pr++) {
        float g0 = p[(2 * pr) * 32];
        float g1 = p[(2 * pr + 1) * 32];
        w[pr] = __builtin_amdgcn_perm(fbits(g1), fbits(g0), 0x07060302u);
    }
    X[tid] = w;
}

// Pass 2: conv from fragment-order X. Block = 128 thr (2 waves), wave owns 2 w's.
// One dwordx4 per (site,kidx) fragment: 1 KB contiguous per wave-instruction.
__global__ __launch_bounds__(128) void k_conv(
    const uint16_t* __restrict__ X, const uint16_t* __restrict__ ktb,
    const float* __restrict__ bias,
    float* __restrict__ outU, float* __restrict__ outL,
    float* __restrict__ buO, float* __restrict__ blO)
{
    int l   = threadIdx.x & 63;
    int wid = threadIdx.x >> 6;
    int o   = l & 31;
    int ch  = l >> 5;

    // XCD decode: b = XCD; within chunk UL outer (X image L2-fits), h innermost.
    int bid  = blockIdx.x;                  // 4096 blocks
    int virt = (bid & 7) * 512 + (bid >> 3);
    int h    = virt & 31;
    int wpp  = (virt >> 5) & 7;
    int UL   = (virt >> 8) & 1;
    int b    = virt >> 9;
    int w0   = wpp * 4 + wid * 2;           // wave's first owned w
    int img  = b * 2 + UL;

    float* dst  = UL ? outL : outU;
    float* bdst = UL ? blO : buO;

    float bp = 0.f;
    f32x16 acc[2][2];
    #pragma unroll
    for (int a = 0; a < 2; a++)
        #pragma unroll
        for (int c = 0; c < 2; c++) acc[a][c] = (f32x16)0.f;

    bool sval[4] = { w0 != 0, true, true, w0 != 30 };
    const char* XB = (const char*)X;

    for (int r = 0; r < 3; r++) {
        int hh = h + 1 - r;
        if ((unsigned)hh >= 32u) continue;          // wave-uniform

        // per-site fragment pointers (l*16 folded in; kidx via imm offset)
        const char* ps[4];
        #pragma unroll
        for (int si = 0; si < 4; si++) {
            int ww = w0 - 1 + si;
            int wwc = ((unsigned)ww < 32u) ? ww : 0;
            size_t off = ((size_t)(img * 1024 + hh * 32 + wwc)) * 4096 + (size_t)l * 16;
            ps[si] = XB + off;
        }

        #pragma unroll
        for (int kidx = 0; kidx < 4; kidx++) {
            short8 A[3][2];
            #pragma unroll
            for (int kw = 0; kw < 3; kw++)
                #pragma unroll
                for (int c = 0; c < 2; c++)
                    A[kw][c] = *(const short8*)&ktb[(((r * 3 + kw) * 64) + c * 32 + (l & 31)) * 64
                                                    + kidx * 16 + ch * 8];

            // load 4 fragments (1 dwordx4 each, imm offset kidx*1024)
            uint4v bw[4];
            #pragma unroll
            for (int si = 0; si < 4; si++) {
                if (sval[si]) bw[si] = *(const uint4v*)(ps[si] + kidx * 1024);
                else          bw[si] = (uint4v)0u;
            }

            // bias from bf16 (center row, own columns: sites 1,2)
            if (r == 1) {
                float4 b0 = *(const float4*)(bias + kidx * 16 + ch * 8);
                float4 b1 = *(const float4*)(bias + kidx * 16 + ch * 8 + 4);
                float bb[8] = {b0.x, b0.y, b0.z, b0.w, b1.x, b1.y, b1.z, b1.w};
                #pragma unroll
                for (int pr = 0; pr < 4; pr++) {
                    bp = fmaf(bflo(bw[1][pr]), bb[2 * pr],
                         fmaf(bfhi(bw[1][pr]), bb[2 * pr + 1], bp));
                    bp = fmaf(bflo(bw[2][pr]), bb[2 * pr],
                         fmaf(bfhi(bw[2][pr]), bb[2 * pr + 1], bp));
                }
            }

            #pragma unroll
            for (int si = 0; si < 4; si++) {
                short8 Bf = __builtin_bit_cast(short8, bw[si]);
                #pragma unroll
                for (int tw = 0; tw < 2; tw++) {
                    int kw = tw + 2 - si;              // compile-time under unroll
                    if (kw >= 0 && kw <= 2) {
                        #pragma unroll
                        for (int c = 0; c < 2; c++)
                            acc[tw][c] = __builtin_amdgcn_mfma_f32_32x32x16_bf16(
                                A[kw][c], Bf, acc[tw][c], 0, 0, 0);
                    }
                }
            }
        }
    }

    // bias reduction: lanes l, l^32 share o
    bp += __shfl_xor(bp, 32);
    if (l < 32) atomicAdd(&bdst[b * 32 + o], bp);

    // stores: col = o (coalesced), row = (reg&3)+8*(reg>>2)+4*(lane>>5)
    #pragma unroll
    for (int tw = 0; tw < 2; tw++) {
        int w = w0 + tw;
        #pragma unroll
        for (int c = 0; c < 2; c++) {
            float* base = dst + ((size_t)b * 65536 + (size_t)(h * 32 + w) * 64 + c * 32) * 32;
            #pragma unroll
            for (int reg = 0; reg < 16; reg++) {
                int row = (reg & 3) + 8 * (reg >> 2) + 4 * (l >> 5);
                base[row * 32 + o] = acc[tw][c][reg];
            }
        }
    }
}

// ---------------- fallback (R12): direct fp32 gather, used if ws too small ----
__global__ __launch_bounds__(64, 3) void k_fallback(
    const float* __restrict__ wu, const float* __restrict__ wl,
    const uint16_t* __restrict__ ktb, const float* __restrict__ bias,
    float* __restrict__ outU, float* __restrict__ outL,
    float* __restrict__ buO, float* __restrict__ blO)
{
    int l  = threadIdx.x;
    int o  = l & 31;
    int ch = l >> 5;
    int bid  = blockIdx.x;
    int virt = (bid & 7) * 1024 + (bid >> 3);
    int h    = virt & 31;
    int wp   = (virt >> 5) & 15;
    int UL   = (virt >> 9) & 1;
    int b    = virt >> 10;
    int w0   = wp * 2;

    const float* src = UL ? wl : wu;
    float* dst  = UL ? outL : outU;
    float* bdst = UL ? blO : buO;

    float bp = 0.f;
    f32x16 acc[2][2];
    #pragma unroll
    for (int a = 0; a < 2; a++)
        #pragma unroll
        for (int c = 0; c < 2; c++) acc[a][c] = (f32x16)0.f;

    bool sv0 = (w0 != 0), sv3 = (w0 != 30);

    for (int r = 0; r < 3; r++) {
        int hh = h + 1 - r;
        if ((unsigned)hh >= 32u) continue;
        const float* sb[4];
        #pragma unroll
        for (int si = 0; si < 4; si++) {
            int ww = w0 - 1 + si;
            int wwc = ((unsigned)ww < 32u) ? ww : 0;
            sb[si] = src + ((size_t)b * 65536 + (size_t)(hh * 32 + wwc) * 64) * 32
                         + ch * 256 + o;
        }
        #pragma unroll
        for (int kidx = 0; kidx < 4; kidx++) {
            short8 A[3][2];
            #pragma unroll
            for (int kw = 0; kw < 3; kw++)
                #pragma unroll
                for (int c = 0; c < 2; c++)
                    A[kw][c] = *(const short8*)&ktb[(((r * 3 + kw) * 64) + c * 32 + (l & 31)) * 64
                                                    + kidx * 16 + ch * 8];
            float g[4][8];
            #pragma unroll
            for (int si = 0; si < 4; si++) {
                bool valid = (si == 0) ? sv0 : (si == 3) ? sv3 : true;
                if (valid) {
                    #pragma unroll
                    for (int e = 0; e < 8; e++) g[si][e] = sb[si][kidx * 512 + e * 32];
                } else {
                    #pragma unroll
                    for (int e = 0; e < 8; e++) g[si][e] = 0.f;
                }
            }
            if (r == 1) {
                float4 b0 = *(const float4*)(bias + kidx * 16 + ch * 8);
                float4 b1 = *(const float4*)(bias + kidx * 16 + ch * 8 + 4);
                float bb[8] = {b0.x, b0.y, b0.z, b0.w, b1.x, b1.y, b1.z, b1.w};
                #pragma unroll
                for (int e = 0; e < 8; e++)
                    bp = fmaf(g[1][e], bb[e], fmaf(g[2][e], bb[e], bp));
            }
            #pragma unroll
            for (int si = 0; si < 4; si++) {
                short8 Bf;
                #pragma unroll
                for (int e = 0; e < 8; e++) Bf[e] = (short)(uint16_t)f2bf(g[si][e]);
                #pragma unroll
                for (int tw = 0; tw < 2; tw++) {
                    int kw = tw + 2 - si;
                    if (kw >= 0 && kw <= 2) {
                        #pragma unroll
                        for (int c = 0; c < 2; c++)
                            acc[tw][c] = __builtin_amdgcn_mfma_f32_32x32x16_bf16(
                                A[kw][c], Bf, acc[tw][c], 0, 0, 0);
                    }
                }
            }
        }
    }
    bp += __shfl_xor(bp, 32);
    if (l < 32) atomicAdd(&bdst[b * 32 + o], bp);
    #pragma unroll
    for (int tw = 0; tw < 2; tw++) {
        int w = w0 + tw;
        #pragma unroll
        for (int c = 0; c < 2; c++) {
            float* base = dst + ((size_t)b * 65536 + (size_t)(h * 32 + w) * 64 + c * 32) * 32;
            #pragma unroll
            for (int reg = 0; reg < 16; reg++) {
                int row = (reg & 3) + 8 * (reg >> 2) + 4 * (l >> 5);
                base[row * 32 + o] = acc[tw][c][reg];
            }
        }
    }
}

extern "C" void kernel_launch(void* const* d_in, const int* in_sizes, int n_in,
                              void* d_out, int out_size, void* d_ws, size_t ws_size,
                              hipStream_t stream) {
    const float* wu   = (const float*)d_in[1];
    const float* buI  = (const float*)d_in[2];
    const float* wl   = (const float*)d_in[3];
    const float* blI  = (const float*)d_in[4];
    const float* kk   = (const float*)d_in[5];
    const float* bias = (const float*)d_in[6];

    float* out  = (float*)d_out;
    float* outU = out;
    float* buO  = out + 16777216;
    float* outL = out + 16777216 + 256;
    float* blO  = out + 2 * 16777216 + 256;

    uint16_t* ktb = (uint16_t*)d_ws;                       // 73728 B
    const size_t XOFF = 131072;                            // 128 KiB, aligned
    const size_t NEED = XOFF + 67108864;                   // + 64 MiB X

    k_prep<<<146, 256, 0, stream>>>(kk, ktb, buI, blI, buO, blO);

    if (ws_size >= NEED) {
        uint4v* X = (uint4v*)((char*)d_ws + XOFF);
        k_xform<<<16384, 256, 0, stream>>>(wu, wl, X);
        k_conv<<<4096, 128, 0, stream>>>((const uint16_t*)X, ktb, bias,
                                         outU, outL, buO, blO);
    } else {
        k_fallback<<<8192, 64, 0, stream>>>(wu, wl, ktb, bias, outU, outL, buO, blO);
    }
}

// Round 14
// 132.687 us; speedup vs baseline: 1.0152x; 1.0152x over previous
//
#include <hip/hip_runtime.h>
#include <cstdint>

typedef __attribute__((ext_vector_type(8))) short short8;
typedef __attribute__((ext_vector_type(16))) float f32x16;
typedef __attribute__((ext_vector_type(4))) unsigned int uint4v;

__device__ inline uint32_t f2bf(float f) {
    union { float f; uint32_t u; } x; x.f = f;
    return (x.u + 0x7FFF + ((x.u >> 16) & 1)) >> 16;
}
__device__ inline uint32_t fbits(float f) {
    union { float f; uint32_t u; } x; x.f = f;
    return x.u;
}
__device__ inline float bflo(uint32_t u) {
    union { uint32_t u; float f; } x; x.u = u << 16; return x.f;
}
__device__ inline float bfhi(uint32_t u) {
    union { uint32_t u; float f; } x; x.u = u & 0xFFFF0000u; return x.f;
}

// Pass 1: build X (bf16) in MFMA-fragment order; also fold in prep
// (kernel->bf16 ktb, bias output init) on the first 37376 threads.
// tid <-> 16-B piece: tid = ((img*1024 + site)*4 + kidx)*64 + l
//   piece elem e: value = src[b][site][co][o], co = kidx*16+(l>>5)*8+e, o = l&31.
__global__ __launch_bounds__(256) void k_xform(
    const float* __restrict__ wu, const float* __restrict__ wl,
    uint4v* __restrict__ X,
    const float* __restrict__ kk, uint16_t* __restrict__ ktb,
    const float* __restrict__ buI, const float* __restrict__ blI,
    float* __restrict__ buO, float* __restrict__ blO)
{
    int tid  = blockIdx.x * 256 + threadIdx.x;   // 16384 blocks -> 4Mi pieces

    if (tid < 36864 + 512) {                     // folded prep
        if (tid < 36864) ktb[tid] = (uint16_t)f2bf(kk[tid]);
        else if (tid < 36864 + 256) buO[tid - 36864] = buI[tid - 36864];
        else blO[tid - 36864 - 256] = blI[tid - 36864 - 256];
    }

    int l    = tid & 63;
    int kidx = (tid >> 6) & 3;
    int site = (tid >> 8) & 1023;
    int img  = tid >> 18;                        // b*2 + src
    int b    = img >> 1;
    const float* src = (img & 1) ? wl : wu;
    int o = l & 31, ch = l >> 5;

    const float* p = src + ((size_t)b * 65536 + (size_t)site * 64
                            + kidx * 16 + ch * 8) * 32 + o;
    uint4v w;
    #pragma unroll
    for (int pr = 0; pr < 4; pr++) {
        float g0 = p[(2 * pr) * 32];
        float g1 = p[(2 * pr + 1) * 32];
        w[pr] = __builtin_amdgcn_perm(fbits(g1), fbits(g0), 0x07060302u);
    }
    X[tid] = w;
}

// Pass 2: conv from fragment-order X. 2048 blocks = (b=XCD, wpp, h), 128 thr.
// UL serialized INSIDE the block so each XCD's live X working set = ONE image
// (4 MiB, L2-fit). Per row: all 16 fragments loaded up-front (16-deep MLP).
__global__ __launch_bounds__(128) void k_conv(
    const uint16_t* __restrict__ X, const uint16_t* __restrict__ ktb,
    const float* __restrict__ bias,
    float* __restrict__ outU, float* __restrict__ outL,
    float* __restrict__ buO, float* __restrict__ blO)
{
    int l   = threadIdx.x & 63;
    int wid = threadIdx.x >> 6;
    int o   = l & 31;
    int ch  = l >> 5;

    int bid = blockIdx.x;                   // 2048
    int b   = bid & 7;                      // image pair <-> XCD (bid%8 mapping)
    int v2  = bid >> 3;                     // 0..255
    int h   = v2 & 31;
    int wpp = v2 >> 5;                      // 0..7
    int w0  = wpp * 4 + wid * 2;            // wave's first owned w

    bool sval[4] = { w0 != 0, true, true, w0 != 30 };
    const char* XB = (const char*)X;

    for (int UL = 0; UL < 2; UL++) {
        int img = b * 2 + UL;
        float* dst  = UL ? outL : outU;
        float* bdst = UL ? blO : buO;

        float bp = 0.f;
        f32x16 acc[2][2];
        #pragma unroll
        for (int a = 0; a < 2; a++)
            #pragma unroll
            for (int c = 0; c < 2; c++) acc[a][c] = (f32x16)0.f;

        for (int r = 0; r < 3; r++) {
            int hh = h + 1 - r;
            if ((unsigned)hh >= 32u) continue;          // wave-uniform

            // ---- load ALL 16 fragments of this row up-front (16-deep) ----
            uint4v bw[4][4];                            // [si][kidx]
            #pragma unroll
            for (int si = 0; si < 4; si++) {
                int ww = w0 - 1 + si;
                int wwc = ((unsigned)ww < 32u) ? ww : 0;
                const char* ps = XB + ((size_t)(img * 1024 + hh * 32 + wwc)) * 4096
                                    + (size_t)l * 16;
                if (sval[si]) {
                    #pragma unroll
                    for (int kidx = 0; kidx < 4; kidx++)
                        bw[si][kidx] = *(const uint4v*)(ps + kidx * 1024);
                } else {
                    #pragma unroll
                    for (int kidx = 0; kidx < 4; kidx++) bw[si][kidx] = (uint4v)0u;
                }
            }

            // ---- consume: per kidx, A-frags + bias + 12 MFMA ----
            #pragma unroll
            for (int kidx = 0; kidx < 4; kidx++) {
                short8 A[3][2];
                #pragma unroll
                for (int kw = 0; kw < 3; kw++)
                    #pragma unroll
                    for (int c = 0; c < 2; c++)
                        A[kw][c] = *(const short8*)&ktb[(((r * 3 + kw) * 64) + c * 32 + (l & 31)) * 64
                                                        + kidx * 16 + ch * 8];

                if (r == 1) {       // bias: center row, own columns (sites 1,2)
                    float4 b0 = *(const float4*)(bias + kidx * 16 + ch * 8);
                    float4 b1 = *(const float4*)(bias + kidx * 16 + ch * 8 + 4);
                    float bb[8] = {b0.x, b0.y, b0.z, b0.w, b1.x, b1.y, b1.z, b1.w};
                    #pragma unroll
                    for (int pr = 0; pr < 4; pr++) {
                        bp = fmaf(bflo(bw[1][kidx][pr]), bb[2 * pr],
                             fmaf(bfhi(bw[1][kidx][pr]), bb[2 * pr + 1], bp));
                        bp = fmaf(bflo(bw[2][kidx][pr]), bb[2 * pr],
                             fmaf(bfhi(bw[2][kidx][pr]), bb[2 * pr + 1], bp));
                    }
                }

                #pragma unroll
                for (int si = 0; si < 4; si++) {
                    short8 Bf = __builtin_bit_cast(short8, bw[si][kidx]);
                    #pragma unroll
                    for (int tw = 0; tw < 2; tw++) {
                        int kw = tw + 2 - si;           // compile-time under unroll
                        if (kw >= 0 && kw <= 2) {
                            #pragma unroll
                            for (int c = 0; c < 2; c++)
                                acc[tw][c] = __builtin_amdgcn_mfma_f32_32x32x16_bf16(
                                    A[kw][c], Bf, acc[tw][c], 0, 0, 0);
                        }
                    }
                }
            }
        }

        // bias reduction: lanes l, l^32 share o
        bp += __shfl_xor(bp, 32);
        if (l < 32) atomicAdd(&bdst[b * 32 + o], bp);

        // stores: col = o (coalesced), row = (reg&3)+8*(reg>>2)+4*(lane>>5)
        #pragma unroll
        for (int tw = 0; tw < 2; tw++) {
            int w = w0 + tw;
            #pragma unroll
            for (int c = 0; c < 2; c++) {
                float* base = dst + ((size_t)b * 65536 + (size_t)(h * 32 + w) * 64 + c * 32) * 32;
                #pragma unroll
                for (int reg = 0; reg < 16; reg++) {
                    int row = (reg & 3) + 8 * (reg >> 2) + 4 * (l >> 5);
                    base[row * 32 + o] = acc[tw][c][reg];
                }
            }
        }
    }
}

extern "C" void kernel_launch(void* const* d_in, const int* in_sizes, int n_in,
                              void* d_out, int out_size, void* d_ws, size_t ws_size,
                              hipStream_t stream) {
    const float* wu   = (const float*)d_in[1];
    const float* buI  = (const float*)d_in[2];
    const float* wl   = (const float*)d_in[3];
    const float* blI  = (const float*)d_in[4];
    const float* kk   = (const float*)d_in[5];
    const float* bias = (const float*)d_in[6];

    float* out  = (float*)d_out;
    float* outU = out;
    float* buO  = out + 16777216;
    float* outL = out + 16777216 + 256;
    float* blO  = out + 2 * 16777216 + 256;

    uint16_t* ktb = (uint16_t*)d_ws;                       // 73728 B
    const size_t XOFF = 131072;                            // 128 KiB aligned
    uint4v* X = (uint4v*)((char*)d_ws + XOFF);             // 64 MiB (R13 proved ws fits)

    k_xform<<<16384, 256, 0, stream>>>(wu, wl, X, kk, ktb, buI, blI, buO, blO);
    k_conv<<<2048, 128, 0, stream>>>((const uint16_t*)X, ktb, bias,
                                     outU, outL, buO, blO);
}